// Round 1
// baseline (1826.127 us; speedup 1.0000x reference)
//
#include <hip/hip_runtime.h>

#define DD 512

// ---------------- GEMM: C[M,512] = A[M,512] @ B[512,512], f32 ----------------
// BM=64, BN=64, BK=16; 256 threads (16x16), each computes a 4x4 micro-tile.
__global__ __launch_bounds__(256) void gemm64(const float* __restrict__ A,
                                              const float* __restrict__ B,
                                              float* __restrict__ C, int M) {
  __shared__ float As[16][65];   // [k][m], +1 pad
  __shared__ float Bs[16][65];   // [k][n], +1 pad
  const int tid = threadIdx.x;
  const int bn = blockIdx.x;       // 0..7
  const int bm = blockIdx.y;       // row-tile
  const int row0 = bm * 64;
  const int col0 = bn * 64;
  const int ty = tid >> 4, tx = tid & 15;

  // load-index decomposition
  const int arow = tid >> 2;            // 0..63
  const int akg  = (tid & 3) * 4;       // 0,4,8,12
  const int brow = tid >> 4;            // 0..15
  const int bng  = (tid & 15) * 4;      // 0..60

  float acc[4][4] = {};

  for (int k0 = 0; k0 < DD; k0 += 16) {
    // stage A tile (64 rows x 16 k)
    float4 av = make_float4(0.f, 0.f, 0.f, 0.f);
    const int gr = row0 + arow;
    if (gr < M) av = *(const float4*)(A + (size_t)gr * DD + k0 + akg);
    As[akg + 0][arow] = av.x;
    As[akg + 1][arow] = av.y;
    As[akg + 2][arow] = av.z;
    As[akg + 3][arow] = av.w;
    // stage B tile (16 k x 64 n)
    const float4 bv = *(const float4*)(B + (size_t)(k0 + brow) * DD + col0 + bng);
    Bs[brow][bng + 0] = bv.x;
    Bs[brow][bng + 1] = bv.y;
    Bs[brow][bng + 2] = bv.z;
    Bs[brow][bng + 3] = bv.w;
    __syncthreads();

#pragma unroll
    for (int k = 0; k < 16; ++k) {
      float a[4], b[4];
#pragma unroll
      for (int i = 0; i < 4; ++i) a[i] = As[k][ty * 4 + i];
#pragma unroll
      for (int j = 0; j < 4; ++j) b[j] = Bs[k][tx * 4 + j];
#pragma unroll
      for (int i = 0; i < 4; ++i)
#pragma unroll
        for (int j = 0; j < 4; ++j) acc[i][j] = fmaf(a[i], b[j], acc[i][j]);
    }
    __syncthreads();
  }

#pragma unroll
  for (int i = 0; i < 4; ++i) {
    const int gr = row0 + ty * 4 + i;
    if (gr < M) {
      float4 v = make_float4(acc[i][0], acc[i][1], acc[i][2], acc[i][3]);
      *(float4*)(C + (size_t)gr * DD + col0 + tx * 4) = v;
    }
  }
}

// ------------- zero masked rows of x (mask on feat == mask on x) -------------
__global__ void zero_rows(float* __restrict__ x, const int* __restrict__ mask) {
  const int r = mask[blockIdx.x];
  *(float4*)(x + (size_t)r * DD + threadIdx.x * 4) = make_float4(0.f, 0.f, 0.f, 0.f);
}

// ------------- per-edge scatter: out[dst] += val * x[src] --------------------
__global__ __launch_bounds__(256) void scatter(const float* __restrict__ x,
                                               const float* __restrict__ ev,
                                               const int* __restrict__ src,
                                               const int* __restrict__ dst,
                                               float* __restrict__ out) {
  const int e = blockIdx.x;
  const int t = threadIdx.x;          // 0..255, 2 floats each
  const int s = src[e];
  const int d = dst[e];
  const float v = ev[e];
  const float2 xv = *(const float2*)(x + (size_t)s * DD + t * 2);
  atomicAdd(out + (size_t)d * DD + t * 2,     xv.x * v);
  atomicAdd(out + (size_t)d * DD + t * 2 + 1, xv.y * v);
}

// ------------- write mask_idx as float into output tail ----------------------
__global__ void mask_tail(const int* __restrict__ mask, float* __restrict__ out_tail,
                          int nm) {
  const int i = blockIdx.x * blockDim.x + threadIdx.x;
  if (i < nm) out_tail[i] = (float)mask[i];
}

extern "C" void kernel_launch(void* const* d_in, const int* in_sizes, int n_in,
                              void* d_out, int out_size, void* d_ws, size_t ws_size,
                              hipStream_t stream) {
  const float* feat     = (const float*)d_in[0];
  const float* weight   = (const float*)d_in[1];
  const float* edge_val = (const float*)d_in[2];
  const int*   edge_src = (const int*)d_in[3];
  const int*   edge_dst = (const int*)d_in[4];
  const int*   mask_idx = (const int*)d_in[5];

  const int n_nodes = in_sizes[0] / DD;   // 50000
  const int n_edges = in_sizes[2];        // 400000
  const int n_mask  = in_sizes[5];        // 15000

  float* out = (float*)d_out;
  float* x   = (float*)d_ws;              // n_nodes*512 f32 = 102.4 MB scratch

  // out matrix region must be zeroed every call (atomic accumulation; harness
  // does not re-poison between replays).
  hipMemsetAsync(d_out, 0, (size_t)n_nodes * DD * sizeof(float), stream);

  dim3 grid(DD / 64, (n_nodes + 63) / 64);
  gemm64<<<grid, 256, 0, stream>>>(feat, weight, x, n_nodes);

  zero_rows<<<n_mask, 128, 0, stream>>>(x, mask_idx);

  scatter<<<n_edges, 256, 0, stream>>>(x, edge_val, edge_src, edge_dst, out);

  mask_tail<<<(n_mask + 255) / 256, 256, 0, stream>>>(mask_idx, out + (size_t)n_nodes * DD, n_mask);
}

// Round 2
// 698.696 us; speedup vs baseline: 2.6136x; 2.6136x over previous
//
#include <hip/hip_runtime.h>

#define DD 512
#define SCAN_B 256

// ---------------- GEMM: C[M,512] = A[M,512] @ B[512,512], f32 ----------------
__global__ __launch_bounds__(256) void gemm64(const float* __restrict__ A,
                                              const float* __restrict__ B,
                                              float* __restrict__ C, int M) {
  __shared__ float As[16][65];
  __shared__ float Bs[16][65];
  const int tid = threadIdx.x;
  const int bn = blockIdx.x;
  const int bm = blockIdx.y;
  const int row0 = bm * 64;
  const int col0 = bn * 64;
  const int ty = tid >> 4, tx = tid & 15;

  const int arow = tid >> 2;
  const int akg  = (tid & 3) * 4;
  const int brow = tid >> 4;
  const int bng  = (tid & 15) * 4;

  float acc[4][4] = {};

  for (int k0 = 0; k0 < DD; k0 += 16) {
    float4 av = make_float4(0.f, 0.f, 0.f, 0.f);
    const int gr = row0 + arow;
    if (gr < M) av = *(const float4*)(A + (size_t)gr * DD + k0 + akg);
    As[akg + 0][arow] = av.x;
    As[akg + 1][arow] = av.y;
    As[akg + 2][arow] = av.z;
    As[akg + 3][arow] = av.w;
    const float4 bv = *(const float4*)(B + (size_t)(k0 + brow) * DD + col0 + bng);
    Bs[brow][bng + 0] = bv.x;
    Bs[brow][bng + 1] = bv.y;
    Bs[brow][bng + 2] = bv.z;
    Bs[brow][bng + 3] = bv.w;
    __syncthreads();

#pragma unroll
    for (int k = 0; k < 16; ++k) {
      float a[4], b[4];
#pragma unroll
      for (int i = 0; i < 4; ++i) a[i] = As[k][ty * 4 + i];
#pragma unroll
      for (int j = 0; j < 4; ++j) b[j] = Bs[k][tx * 4 + j];
#pragma unroll
      for (int i = 0; i < 4; ++i)
#pragma unroll
        for (int j = 0; j < 4; ++j) acc[i][j] = fmaf(a[i], b[j], acc[i][j]);
    }
    __syncthreads();
  }

#pragma unroll
  for (int i = 0; i < 4; ++i) {
    const int gr = row0 + ty * 4 + i;
    if (gr < M) {
      float4 v = make_float4(acc[i][0], acc[i][1], acc[i][2], acc[i][3]);
      *(float4*)(C + (size_t)gr * DD + col0 + tx * 4) = v;
    }
  }
}

// ------------- zero masked rows of x (mask on feat == mask on x) -------------
__global__ void zero_rows(float* __restrict__ x, const int* __restrict__ mask) {
  const int r = mask[blockIdx.x];
  *(float4*)(x + (size_t)r * DD + threadIdx.x * 4) = make_float4(0.f, 0.f, 0.f, 0.f);
}

// ------------------------------ counting sort --------------------------------
__global__ __launch_bounds__(256) void hist(const int* __restrict__ dst,
                                            int* __restrict__ counts, int n) {
  const int i = blockIdx.x * blockDim.x + threadIdx.x;
  if (i < n) atomicAdd(&counts[dst[i]], 1);
}

// per-256-chunk exclusive scan; block totals out
__global__ __launch_bounds__(SCAN_B) void scanA(const int* __restrict__ counts,
                                                int* __restrict__ lscan,
                                                int* __restrict__ blockSums, int n) {
  __shared__ int sm[SCAN_B];
  const int t = threadIdx.x;
  const int i = blockIdx.x * SCAN_B + t;
  const int v = (i < n) ? counts[i] : 0;
  sm[t] = v;
  __syncthreads();
  for (int off = 1; off < SCAN_B; off <<= 1) {
    int add = (t >= off) ? sm[t - off] : 0;
    __syncthreads();
    sm[t] += add;
    __syncthreads();
  }
  if (i < n) lscan[i] = sm[t] - v;              // exclusive
  if (t == SCAN_B - 1) blockSums[blockIdx.x] = sm[t];
}

// single-block exclusive scan of block sums (nb <= 256)
__global__ __launch_bounds__(SCAN_B) void scanB(int* __restrict__ blockSums, int nb) {
  __shared__ int sm[SCAN_B];
  const int t = threadIdx.x;
  const int v = (t < nb) ? blockSums[t] : 0;
  sm[t] = v;
  __syncthreads();
  for (int off = 1; off < SCAN_B; off <<= 1) {
    int add = (t >= off) ? sm[t - off] : 0;
    __syncthreads();
    sm[t] += add;
    __syncthreads();
  }
  if (t < nb) blockSums[t] = sm[t] - v;          // exclusive base
}

__global__ __launch_bounds__(SCAN_B) void scanC(int* __restrict__ lscan,
                                                const int* __restrict__ blockBase,
                                                int* __restrict__ cursor, int n) {
  const int i = blockIdx.x * SCAN_B + threadIdx.x;
  if (i < n) {
    const int o = lscan[i] + blockBase[blockIdx.x];
    lscan[i] = o;         // final exclusive offsets
    cursor[i] = o;        // scatter cursor copy
  }
}

__global__ __launch_bounds__(256) void scatter_sort(const int* __restrict__ src,
                                                    const int* __restrict__ dst,
                                                    const float* __restrict__ ev,
                                                    int* __restrict__ cursor,
                                                    int* __restrict__ ssrc,
                                                    float* __restrict__ sval, int n) {
  const int i = blockIdx.x * blockDim.x + threadIdx.x;
  if (i < n) {
    const int pos = atomicAdd(&cursor[dst[i]], 1);
    ssrc[pos] = src[i];
    sval[pos] = ev[i];
  }
}

// ------------- per-node accumulation: out[node] = sum val*x[src] -------------
// 128 threads/block, float4 per thread (512 f32 per row)
__global__ __launch_bounds__(128) void aggregate(const float* __restrict__ x,
                                                 const int* __restrict__ ssrc,
                                                 const float* __restrict__ sval,
                                                 const int* __restrict__ offsets,
                                                 const int* __restrict__ counts,
                                                 float* __restrict__ out) {
  const int node = blockIdx.x;
  const int t = threadIdx.x;
  const int b = offsets[node];
  const int c = counts[node];
  float4 acc = make_float4(0.f, 0.f, 0.f, 0.f);
  for (int j = 0; j < c; ++j) {
    const int s = ssrc[b + j];
    const float v = sval[b + j];
    const float4 xv = *(const float4*)(x + (size_t)s * DD + t * 4);
    acc.x = fmaf(v, xv.x, acc.x);
    acc.y = fmaf(v, xv.y, acc.y);
    acc.z = fmaf(v, xv.z, acc.z);
    acc.w = fmaf(v, xv.w, acc.w);
  }
  *(float4*)(out + (size_t)node * DD + t * 4) = acc;
}

// ------------- write mask_idx as float into output tail ----------------------
__global__ void mask_tail(const int* __restrict__ mask, float* __restrict__ out_tail,
                          int nm) {
  const int i = blockIdx.x * blockDim.x + threadIdx.x;
  if (i < nm) out_tail[i] = (float)mask[i];
}

extern "C" void kernel_launch(void* const* d_in, const int* in_sizes, int n_in,
                              void* d_out, int out_size, void* d_ws, size_t ws_size,
                              hipStream_t stream) {
  const float* feat     = (const float*)d_in[0];
  const float* weight   = (const float*)d_in[1];
  const float* edge_val = (const float*)d_in[2];
  const int*   edge_src = (const int*)d_in[3];
  const int*   edge_dst = (const int*)d_in[4];
  const int*   mask_idx = (const int*)d_in[5];

  const int n_nodes = in_sizes[0] / DD;   // 50000
  const int n_edges = in_sizes[2];        // 400000
  const int n_mask  = in_sizes[5];        // 15000

  float* out = (float*)d_out;

  // workspace layout
  char* base = (char*)d_ws;
  size_t off = 0;
  auto alloc = [&](size_t bytes) {
    void* p = base + off;
    off = (off + bytes + 255) & ~(size_t)255;
    return p;
  };
  float* x        = (float*)alloc((size_t)n_nodes * DD * sizeof(float)); // 102.4 MB
  int*   counts   = (int*)alloc((size_t)n_nodes * sizeof(int));
  int*   offsets  = (int*)alloc((size_t)n_nodes * sizeof(int));
  int*   cursor   = (int*)alloc((size_t)n_nodes * sizeof(int));
  int*   bsums    = (int*)alloc(SCAN_B * sizeof(int));
  int*   ssrc     = (int*)alloc((size_t)n_edges * sizeof(int));
  float* sval     = (float*)alloc((size_t)n_edges * sizeof(float));

  const int nb = (n_nodes + SCAN_B - 1) / SCAN_B;  // 196 <= 256

  // --- CSR build (independent of GEMM; issue first) ---
  hipMemsetAsync(counts, 0, (size_t)n_nodes * sizeof(int), stream);
  hist<<<(n_edges + 255) / 256, 256, 0, stream>>>(edge_dst, counts, n_edges);
  scanA<<<nb, SCAN_B, 0, stream>>>(counts, offsets, bsums, n_nodes);
  scanB<<<1, SCAN_B, 0, stream>>>(bsums, nb);
  scanC<<<nb, SCAN_B, 0, stream>>>(offsets, bsums, cursor, n_nodes);
  scatter_sort<<<(n_edges + 255) / 256, 256, 0, stream>>>(edge_src, edge_dst, edge_val,
                                                          cursor, ssrc, sval, n_edges);

  // --- x = feat @ W, then zero masked rows ---
  dim3 grid(DD / 64, (n_nodes + 63) / 64);
  gemm64<<<grid, 256, 0, stream>>>(feat, weight, x, n_nodes);
  zero_rows<<<n_mask, 128, 0, stream>>>(x, mask_idx);

  // --- out[node] = sum over incoming edges (writes every row; no pre-zero) ---
  aggregate<<<n_nodes, 128, 0, stream>>>(x, ssrc, sval, offsets, counts, out);

  // --- output 1: mask_idx as float ---
  mask_tail<<<(n_mask + 255) / 256, 256, 0, stream>>>(mask_idx, out + (size_t)n_nodes * DD, n_mask);
}

// Round 3
// 220.995 us; speedup vs baseline: 8.2632x; 3.1616x over previous
//
#include <hip/hip_runtime.h>

#define DD 512
#define SCAN_B 256
typedef unsigned short u16;
typedef unsigned int u32;

typedef __attribute__((ext_vector_type(8))) __bf16 bf16v8;
typedef __attribute__((ext_vector_type(4))) float f32x4;

__device__ __forceinline__ u16 f2bf(float f) {
  u32 u = __builtin_bit_cast(u32, f);
  u32 r = (u + 0x7fffu + ((u >> 16) & 1u)) >> 16;   // RNE
  return (u16)r;
}
__device__ __forceinline__ float bf2f(u32 h) {
  return __builtin_bit_cast(float, h << 16);
}

typedef const __attribute__((address_space(1))) void* gptr_t;
typedef __attribute__((address_space(3))) void* lptr_t;
__device__ __forceinline__ void gload_lds16(const void* g, void* l) {
  __builtin_amdgcn_global_load_lds((gptr_t)g, (lptr_t)l, 16, 0, 0);
}

// ---------------- feat f32 -> bf16, zero-fill pad rows ----------------
__global__ __launch_bounds__(256) void conv_feat(const float* __restrict__ in,
                                                 u16* __restrict__ out,
                                                 int n_real, int n_total) {
  const int i = (blockIdx.x * 256 + threadIdx.x) * 8;
  if (i >= n_total) return;
  u32 pk0 = 0, pk1 = 0, pk2 = 0, pk3 = 0;
  if (i < n_real) {
    const float4 a = *(const float4*)(in + i);
    const float4 b = *(const float4*)(in + i + 4);
    pk0 = f2bf(a.x) | ((u32)f2bf(a.y) << 16);
    pk1 = f2bf(a.z) | ((u32)f2bf(a.w) << 16);
    pk2 = f2bf(b.x) | ((u32)f2bf(b.y) << 16);
    pk3 = f2bf(b.z) | ((u32)f2bf(b.w) << 16);
  }
  *(uint4*)(out + i) = make_uint4(pk0, pk1, pk2, pk3);
}

// ---------------- W[k][n] f32 -> Wt[n][k] bf16 (LDS-tiled transpose) ----------------
__global__ __launch_bounds__(256) void wconv_t(const float* __restrict__ W,
                                               u16* __restrict__ Wt) {
  __shared__ float sm[64][65];
  const int bx = blockIdx.x;   // k tile
  const int by = blockIdx.y;   // n tile
  const int t = threadIdx.x;
  const int r = t >> 6;        // 0..3
  const int c = t & 63;
#pragma unroll
  for (int i = 0; i < 64; i += 4)
    sm[i + r][c] = W[(size_t)(bx * 64 + i + r) * DD + by * 64 + c];
  __syncthreads();
#pragma unroll
  for (int i = 0; i < 64; i += 4) {
    const int n = by * 64 + i + r;
    const int k = bx * 64 + c;
    Wt[(size_t)n * DD + k] = f2bf(sm[c][i + r]);
  }
}

// ---------------- MFMA GEMM: X[Mpad,512](bf16) = A[Mpad,512](bf16) @ Wt^T ----------------
// 128x128 tile, BK=32, 4 waves, each wave 64x64 (4x4 frags of 16x16x32).
__global__ __launch_bounds__(256) void gemm_mfma(const u16* __restrict__ A,
                                                 const u16* __restrict__ Bt,
                                                 u16* __restrict__ X) {
  __shared__ __align__(16) u16 ldsA[128 * 32];
  __shared__ __align__(16) u16 ldsB[128 * 32];
  const int tid = threadIdx.x;
  const int lane = tid & 63;
  const int w = tid >> 6;
  const int wm = w >> 1, wn = w & 1;
  const int tm = blockIdx.y;
  const int tn = blockIdx.x;

  const int lr = lane & 15;
  const int kg = lane >> 4;

  f32x4 acc[4][4] = {};

  // staging: chunk c = (w*2+q)*64 + lane; LDS slot (row=c>>2, kc=c&3) holds
  // global kchunk kc ^ ((row>>1)&3)  (XOR swizzle, pre-applied on global src)
  const int c0 = (w * 2 + 0) * 64 + lane;
  const int c1 = (w * 2 + 1) * 64 + lane;
  const int r0 = c0 >> 2, k0c = (c0 & 3) ^ ((r0 >> 1) & 3);
  const int r1 = c1 >> 2, k1c = (c1 & 3) ^ ((r1 >> 1) & 3);

  const u16* ga0 = A + (size_t)(tm * 128 + r0) * DD + k0c * 8;
  const u16* ga1 = A + (size_t)(tm * 128 + r1) * DD + k1c * 8;
  const u16* gb0 = Bt + (size_t)(tn * 128 + r0) * DD + k0c * 8;
  const u16* gb1 = Bt + (size_t)(tn * 128 + r1) * DD + k1c * 8;
  u16* la0 = &ldsA[(w * 2 + 0) * 64 * 8];
  u16* la1 = &ldsA[(w * 2 + 1) * 64 * 8];
  u16* lb0 = &ldsB[(w * 2 + 0) * 64 * 8];
  u16* lb1 = &ldsB[(w * 2 + 1) * 64 * 8];

  for (int k0 = 0; k0 < DD; k0 += 32) {
    gload_lds16(ga0 + k0, la0);
    gload_lds16(ga1 + k0, la1);
    gload_lds16(gb0 + k0, lb0);
    gload_lds16(gb1 + k0, lb1);
    __syncthreads();   // drains vmcnt -> tiles ready

    bf16v8 af[4], bfr[4];
#pragma unroll
    for (int m = 0; m < 4; ++m) {
      const int row = wm * 64 + m * 16 + lr;
      const int kc = kg ^ ((row >> 1) & 3);
      af[m] = *(const bf16v8*)&ldsA[row * 32 + kc * 8];
    }
#pragma unroll
    for (int n = 0; n < 4; ++n) {
      const int col = wn * 64 + n * 16 + lr;
      const int kc = kg ^ ((col >> 1) & 3);
      bfr[n] = *(const bf16v8*)&ldsB[col * 32 + kc * 8];
    }
#pragma unroll
    for (int m = 0; m < 4; ++m)
#pragma unroll
      for (int n = 0; n < 4; ++n)
        acc[m][n] = __builtin_amdgcn_mfma_f32_16x16x32_bf16(af[m], bfr[n], acc[m][n], 0, 0, 0);
    __syncthreads();   // protect LDS before next stage
  }

  // C/D layout (verified): col = lane&15, row = (lane>>4)*4 + reg
  const int crow = (lane >> 4) * 4;
  const int ccol = lane & 15;
#pragma unroll
  for (int m = 0; m < 4; ++m) {
    const int rowb = tm * 128 + wm * 64 + m * 16 + crow;
#pragma unroll
    for (int n = 0; n < 4; ++n) {
      const int col = tn * 128 + wn * 64 + n * 16 + ccol;
#pragma unroll
      for (int r = 0; r < 4; ++r)
        X[(size_t)(rowb + r) * DD + col] = f2bf(acc[m][n][r]);
    }
  }
}

// ------------- zero masked rows of x (bf16) -------------
__global__ void zero_rows(u16* __restrict__ x, const int* __restrict__ mask) {
  const int r = mask[blockIdx.x];
  *(uint4*)(x + (size_t)r * DD + threadIdx.x * 8) = make_uint4(0, 0, 0, 0);
}

// ------------------------------ counting sort --------------------------------
__global__ __launch_bounds__(256) void hist(const int* __restrict__ dst,
                                            int* __restrict__ counts, int n) {
  const int i = blockIdx.x * blockDim.x + threadIdx.x;
  if (i < n) atomicAdd(&counts[dst[i]], 1);
}

__global__ __launch_bounds__(SCAN_B) void scanA(const int* __restrict__ counts,
                                                int* __restrict__ lscan,
                                                int* __restrict__ blockSums, int n) {
  __shared__ int sm[SCAN_B];
  const int t = threadIdx.x;
  const int i = blockIdx.x * SCAN_B + t;
  const int v = (i < n) ? counts[i] : 0;
  sm[t] = v;
  __syncthreads();
  for (int off = 1; off < SCAN_B; off <<= 1) {
    int add = (t >= off) ? sm[t - off] : 0;
    __syncthreads();
    sm[t] += add;
    __syncthreads();
  }
  if (i < n) lscan[i] = sm[t] - v;
  if (t == SCAN_B - 1) blockSums[blockIdx.x] = sm[t];
}

__global__ __launch_bounds__(SCAN_B) void scanB(int* __restrict__ blockSums, int nb) {
  __shared__ int sm[SCAN_B];
  const int t = threadIdx.x;
  const int v = (t < nb) ? blockSums[t] : 0;
  sm[t] = v;
  __syncthreads();
  for (int off = 1; off < SCAN_B; off <<= 1) {
    int add = (t >= off) ? sm[t - off] : 0;
    __syncthreads();
    sm[t] += add;
    __syncthreads();
  }
  if (t < nb) blockSums[t] = sm[t] - v;
}

__global__ __launch_bounds__(SCAN_B) void scanC(int* __restrict__ lscan,
                                                const int* __restrict__ blockBase,
                                                int* __restrict__ cursor, int n) {
  const int i = blockIdx.x * SCAN_B + threadIdx.x;
  if (i < n) {
    const int o = lscan[i] + blockBase[blockIdx.x];
    lscan[i] = o;
    cursor[i] = o;
  }
}

__global__ __launch_bounds__(256) void scatter_sort(const int* __restrict__ src,
                                                    const int* __restrict__ dst,
                                                    const float* __restrict__ ev,
                                                    int* __restrict__ cursor,
                                                    int* __restrict__ ssrc,
                                                    float* __restrict__ sval, int n) {
  const int i = blockIdx.x * blockDim.x + threadIdx.x;
  if (i < n) {
    const int pos = atomicAdd(&cursor[dst[i]], 1);
    ssrc[pos] = src[i];
    sval[pos] = ev[i];
  }
}

// ------------- per-node accumulation from bf16 x, f32 accumulate -------------
// one wave per node, 4 nodes per 256-thread block
__global__ __launch_bounds__(256) void aggregate(const u16* __restrict__ x,
                                                 const int* __restrict__ ssrc,
                                                 const float* __restrict__ sval,
                                                 const int* __restrict__ offsets,
                                                 const int* __restrict__ counts,
                                                 float* __restrict__ out, int n_nodes) {
  const int node = blockIdx.x * 4 + (threadIdx.x >> 6);
  if (node >= n_nodes) return;
  const int lane = threadIdx.x & 63;
  const int b = offsets[node];
  const int cnt = counts[node];
  float acc[8] = {};
  for (int j = 0; j < cnt; ++j) {
    const int s = ssrc[b + j];
    const float v = sval[b + j];
    const uint4 u = *(const uint4*)(x + (size_t)s * DD + lane * 8);
    acc[0] = fmaf(v, bf2f(u.x & 0xffffu), acc[0]);
    acc[1] = fmaf(v, bf2f(u.x >> 16),     acc[1]);
    acc[2] = fmaf(v, bf2f(u.y & 0xffffu), acc[2]);
    acc[3] = fmaf(v, bf2f(u.y >> 16),     acc[3]);
    acc[4] = fmaf(v, bf2f(u.z & 0xffffu), acc[4]);
    acc[5] = fmaf(v, bf2f(u.z >> 16),     acc[5]);
    acc[6] = fmaf(v, bf2f(u.w & 0xffffu), acc[6]);
    acc[7] = fmaf(v, bf2f(u.w >> 16),     acc[7]);
  }
  float4* o = (float4*)(out + (size_t)node * DD + lane * 8);
  o[0] = make_float4(acc[0], acc[1], acc[2], acc[3]);
  o[1] = make_float4(acc[4], acc[5], acc[6], acc[7]);
}

__global__ void mask_tail(const int* __restrict__ mask, float* __restrict__ out_tail,
                          int nm) {
  const int i = blockIdx.x * blockDim.x + threadIdx.x;
  if (i < nm) out_tail[i] = (float)mask[i];
}

extern "C" void kernel_launch(void* const* d_in, const int* in_sizes, int n_in,
                              void* d_out, int out_size, void* d_ws, size_t ws_size,
                              hipStream_t stream) {
  const float* feat     = (const float*)d_in[0];
  const float* weight   = (const float*)d_in[1];
  const float* edge_val = (const float*)d_in[2];
  const int*   edge_src = (const int*)d_in[3];
  const int*   edge_dst = (const int*)d_in[4];
  const int*   mask_idx = (const int*)d_in[5];

  const int n_nodes = in_sizes[0] / DD;   // 50000
  const int n_edges = in_sizes[2];        // 400000
  const int n_mask  = in_sizes[5];        // 15000

  const int n_tiles_m = (n_nodes + 127) / 128;   // 391
  const int m_pad = n_tiles_m * 128;             // 50048

  float* out = (float*)d_out;

  char* base = (char*)d_ws;
  size_t off = 0;
  auto alloc = [&](size_t bytes) {
    void* p = base + off;
    off = (off + bytes + 255) & ~(size_t)255;
    return p;
  };
  u16*   featb  = (u16*)alloc((size_t)m_pad * DD * sizeof(u16));   // 51.3 MB
  u16*   x      = (u16*)alloc((size_t)m_pad * DD * sizeof(u16));   // 51.3 MB
  u16*   wt     = (u16*)alloc((size_t)DD * DD * sizeof(u16));      // 0.5 MB
  int*   counts = (int*)alloc((size_t)n_nodes * sizeof(int));
  int*   offs   = (int*)alloc((size_t)n_nodes * sizeof(int));
  int*   cursor = (int*)alloc((size_t)n_nodes * sizeof(int));
  int*   bsums  = (int*)alloc(SCAN_B * sizeof(int));
  int*   ssrc   = (int*)alloc((size_t)n_edges * sizeof(int));
  float* sval   = (float*)alloc((size_t)n_edges * sizeof(float));

  const int nb = (n_nodes + SCAN_B - 1) / SCAN_B;  // 196

  // --- CSR build ---
  hipMemsetAsync(counts, 0, (size_t)n_nodes * sizeof(int), stream);
  hist<<<(n_edges + 255) / 256, 256, 0, stream>>>(edge_dst, counts, n_edges);
  scanA<<<nb, SCAN_B, 0, stream>>>(counts, offs, bsums, n_nodes);
  scanB<<<1, SCAN_B, 0, stream>>>(bsums, nb);
  scanC<<<nb, SCAN_B, 0, stream>>>(offs, bsums, cursor, n_nodes);
  scatter_sort<<<(n_edges + 255) / 256, 256, 0, stream>>>(edge_src, edge_dst, edge_val,
                                                          cursor, ssrc, sval, n_edges);

  // --- bf16 conversions ---
  const int n_real  = n_nodes * DD;
  const int n_total = m_pad * DD;
  conv_feat<<<(n_total / 8 + 255) / 256, 256, 0, stream>>>(feat, featb, n_real, n_total);
  dim3 wg(DD / 64, DD / 64);
  wconv_t<<<wg, 256, 0, stream>>>(weight, wt);

  // --- x = feat @ W (bf16 MFMA), then zero masked rows ---
  dim3 grid(DD / 128, n_tiles_m);
  gemm_mfma<<<grid, 256, 0, stream>>>(featb, wt, x);
  zero_rows<<<n_mask, 64, 0, stream>>>(x, mask_idx);

  // --- out[node] = sum val * x[src] ---
  aggregate<<<(n_nodes + 3) / 4, 256, 0, stream>>>(x, ssrc, sval, offs, counts, out, n_nodes);

  // --- output 1: mask_idx as float ---
  mask_tail<<<(n_mask + 255) / 256, 256, 0, stream>>>(mask_idx, out + (size_t)n_nodes * DD, n_mask);
}